// Round 4
// baseline (1821.488 us; speedup 1.0000x reference)
//
#include <hip/hip_runtime.h>
#include <hip/hip_bf16.h>

#define E_DIM 1024
#define HEADS 16
#define DHEAD 64
#define RANK 8
#define BATCH 4
#define SEQ 4096
#define MTOT (BATCH*SEQ)

__device__ __forceinline__ float bf2f(unsigned short u) {
    return __uint_as_float(((unsigned int)u) << 16);
}
__device__ __forceinline__ unsigned short f2bf(float f) {
    unsigned int x = __float_as_uint(f);
    unsigned int r = (x + 0x7fffu + ((x >> 16) & 1u)) >> 16;
    return (unsigned short)r;
}

// ---------------------------------------------------------------------------
// sentinel: report ws_size (MB) through the absmax channel if budget too small
// ---------------------------------------------------------------------------
__global__ __launch_bounds__(256)
void ws_sentinel(float* __restrict__ out, float mb)
{
    out[threadIdx.x] = mb;
}

// ---------------------------------------------------------------------------
// K1: W_eff[g] = W[g] + A[g] @ B[g]   (g = q,k,v; g=3 is Wo passthrough)
// all f32
// ---------------------------------------------------------------------------
__global__ __launch_bounds__(256)
void prep_weights(const float* __restrict__ Wq,
                  const float* __restrict__ Wk,
                  const float* __restrict__ Wv,
                  const float* __restrict__ Wo,
                  const float* __restrict__ qa, const float* __restrict__ qb,
                  const float* __restrict__ ka, const float* __restrict__ kb,
                  const float* __restrict__ va, const float* __restrict__ vb,
                  float* __restrict__ Weff)
{
    int idx = blockIdx.x * 256 + threadIdx.x;    // 0 .. 4*1024*1024-1
    int g  = idx >> 20;
    int cj = idx & 0xFFFFF;
    int c  = cj >> 10;
    int j  = cj & 1023;
    const float* W = (g==0)?Wq:(g==1)?Wk:(g==2)?Wv:Wo;
    float acc = W[cj];
    if (g < 3) {
        const float* A  = (g==0)?qa:(g==1)?ka:va;
        const float* Bm = (g==0)?qb:(g==1)?kb:vb;
        #pragma unroll
        for (int r = 0; r < RANK; ++r)
            acc += A[c*RANK + r] * Bm[r*E_DIM + j];
    }
    Weff[idx] = acc;
}

// ---------------------------------------------------------------------------
// K2: C[M,1024] = X @ W + bias. W is f32 Weff.
// XBF16: input storage. OUTF32: 1 -> f32 output (d_out), 0 -> bf16 output.
// BM=BN=128, BK=8, 256 thr, 8x8 per thread.
// ---------------------------------------------------------------------------
template<int XBF16, int OUTF32>
__global__ __launch_bounds__(256)
void gemm128(const void* __restrict__ Xv, const float* __restrict__ W,
             const float* __restrict__ bias, void* __restrict__ outv)
{
    __shared__ float Xs[8][132];
    __shared__ float Ws[8][132];
    const int tid = threadIdx.x;
    const int tx = tid & 15, ty = tid >> 4;
    const int i0 = blockIdx.y * 128;
    const int j0 = blockIdx.x * 128;
    float acc[8][8] = {};
    for (int k0 = 0; k0 < E_DIM; k0 += 8) {
        if (tid < 128) {                       // stage X panel: 128 rows x 8 k
            const int row = tid;
            if (XBF16) {
                const unsigned short* X = (const unsigned short*)Xv;
                const uint4 u = *(const uint4*)(X + (size_t)(i0+row)*E_DIM + k0);
                const unsigned short* s = (const unsigned short*)&u;
                #pragma unroll
                for (int i = 0; i < 8; ++i) Xs[i][row] = bf2f(s[i]);
            } else {
                const float* X = (const float*)Xv;
                const float* xp = X + (size_t)(i0+row)*E_DIM + k0;
                const float4 u0 = *(const float4*)xp;
                const float4 u1 = *(const float4*)(xp + 4);
                Xs[0][row]=u0.x; Xs[1][row]=u0.y; Xs[2][row]=u0.z; Xs[3][row]=u0.w;
                Xs[4][row]=u1.x; Xs[5][row]=u1.y; Xs[6][row]=u1.z; Xs[7][row]=u1.w;
            }
        } else {                               // stage W panel: 8 k x 128 cols
            const int t2 = tid - 128;
            const int kk = t2 >> 4;
            const int jb = (t2 & 15) * 8;
            const float* wp = W + (size_t)(k0+kk)*E_DIM + j0 + jb;
            *(float4*)&Ws[kk][jb]     = *(const float4*)wp;
            *(float4*)&Ws[kk][jb + 4] = *(const float4*)(wp + 4);
        }
        __syncthreads();
        #pragma unroll
        for (int kk = 0; kk < 8; ++kk) {
            float a[8], b[8];
            *(float4*)&a[0] = *(const float4*)&Xs[kk][ty*8];
            *(float4*)&a[4] = *(const float4*)&Xs[kk][ty*8+4];
            *(float4*)&b[0] = *(const float4*)&Ws[kk][tx*8];
            *(float4*)&b[4] = *(const float4*)&Ws[kk][tx*8+4];
            #pragma unroll
            for (int r = 0; r < 8; ++r)
                #pragma unroll
                for (int c = 0; c < 8; ++c)
                    acc[r][c] = fmaf(a[r], b[c], acc[r][c]);
        }
        __syncthreads();
    }
    #pragma unroll
    for (int r = 0; r < 8; ++r) {
        if (OUTF32) {
            float* out = (float*)outv;
            float o[8];
            #pragma unroll
            for (int c = 0; c < 8; ++c) o[c] = acc[r][c] + bias[j0 + tx*8 + c];
            float* op = out + (size_t)(i0 + ty*8 + r)*E_DIM + j0 + tx*8;
            *(float4*)op       = *(float4*)&o[0];
            *(float4*)(op + 4) = *(float4*)&o[4];
        } else {
            unsigned short* out = (unsigned short*)outv;
            union { unsigned short h[8]; uint4 u; } o;
            #pragma unroll
            for (int c = 0; c < 8; ++c)
                o.h[c] = f2bf(acc[r][c] + bias[j0 + tx*8 + c]);
            *(uint4*)(out + (size_t)(i0 + ty*8 + r)*E_DIM + j0 + tx*8) = o.u;
        }
    }
}

// ---------------------------------------------------------------------------
// K2b: in-place softmax over each head's 64 dims. One wave per (row, head).
// ---------------------------------------------------------------------------
__global__ __launch_bounds__(256)
void q_softmax_inplace(unsigned short* __restrict__ qn)
{
    const int gw   = (blockIdx.x * 256 + threadIdx.x) >> 6;  // 0..262143
    const int lane = threadIdx.x & 63;
    const int row  = gw >> 4;
    const int h    = gw & 15;
    const size_t base = (size_t)row * E_DIM + h * DHEAD;
    float x = bf2f(qn[base + lane]);
    float m = x;
    #pragma unroll
    for (int d = 32; d >= 1; d >>= 1) m = fmaxf(m, __shfl_xor(m, d));
    float e = __expf(x - m);
    float s = e;
    #pragma unroll
    for (int d = 32; d >= 1; d >>= 1) s += __shfl_xor(s, d);
    qn[base + lane] = f2bf(e / s);
}

// ---------------------------------------------------------------------------
// K3a/K3b: column sums of exp(k) over S (the k-softmax denominator)
// ---------------------------------------------------------------------------
__global__ __launch_bounds__(256)
void k_colsum_part(const unsigned short* __restrict__ K, const unsigned char* __restrict__ mask,
                   float* __restrict__ part)
{
    const int e  = blockIdx.x * 256 + threadIdx.x;   // 0..1023
    const int sb = blockIdx.y;                        // 0..15
    const int b  = blockIdx.z;
    const int s0 = sb * 256;
    const unsigned short* kp = K + ((size_t)b*SEQ + s0)*E_DIM + e;
    const unsigned char* mp = mask + b*SEQ + s0;
    float acc = 0.f;
    for (int s = 0; s < 256; ++s) {
        float kv = bf2f(kp[(size_t)s*E_DIM]);
        acc += mp[s] ? 0.f : __expf(kv);
    }
    part[((size_t)b*16 + sb)*E_DIM + e] = acc;
}

__global__ __launch_bounds__(256)
void k_colsum_final(const float* __restrict__ part, float* __restrict__ colsum)
{
    int idx = blockIdx.x * 256 + threadIdx.x;  // 4096
    int b = idx >> 10, e = idx & 1023;
    float s = 0.f;
    for (int p = 0; p < 16; ++p) s += part[((size_t)b*16 + p)*E_DIM + e];
    colsum[idx] = s;
}

__global__ __launch_bounds__(256)
void zero_ctx(float* __restrict__ ctx)
{
    ctx[blockIdx.x * 256 + threadIdx.x] = 0.f;
}

// ---------------------------------------------------------------------------
// K4: ctx[b,h,d,e] += sum_{s in chunk} exp(k[b,s,h,d]) * v[b,s,h,e]
// ---------------------------------------------------------------------------
__global__ __launch_bounds__(256)
void context_partial(const unsigned short* __restrict__ K, const unsigned short* __restrict__ V,
                     const unsigned char* __restrict__ mask, float* __restrict__ ctx)
{
    __shared__ float kx[32][65];
    __shared__ float vx[32][65];
    const int h = blockIdx.x, sb = blockIdx.y, b = blockIdx.z;
    const int tid = threadIdx.x;
    const int tx = tid & 15, ty = tid >> 4;
    float acc[4][4] = {};
    const int sbase = sb * 256;
    for (int sc = 0; sc < 256; sc += 32) {
        const int row = tid >> 3;
        const int cb  = (tid & 7) * 8;
        const int s   = sbase + sc + row;
        const size_t gof = ((size_t)b*SEQ + s)*E_DIM + h*DHEAD + cb;
        const bool msk = mask[b*SEQ + s] != 0;
        uint4 ku = *(const uint4*)(K + gof);
        uint4 vu = *(const uint4*)(V + gof);
        const unsigned short* ks = (const unsigned short*)&ku;
        const unsigned short* vs = (const unsigned short*)&vu;
        #pragma unroll
        for (int c = 0; c < 8; ++c) {
            kx[row][cb+c] = msk ? 0.f : __expf(bf2f(ks[c]));
            vx[row][cb+c] = bf2f(vs[c]);
        }
        __syncthreads();
        #pragma unroll
        for (int kk = 0; kk < 32; ++kk) {
            float a[4], bb[4];
            #pragma unroll
            for (int r = 0; r < 4; ++r) a[r] = kx[kk][ty*4+r];
            #pragma unroll
            for (int c = 0; c < 4; ++c) bb[c] = vx[kk][tx*4+c];
            #pragma unroll
            for (int r = 0; r < 4; ++r)
                #pragma unroll
                for (int c = 0; c < 4; ++c)
                    acc[r][c] = fmaf(a[r], bb[c], acc[r][c]);
        }
        __syncthreads();
    }
    #pragma unroll
    for (int r = 0; r < 4; ++r)
        #pragma unroll
        for (int c = 0; c < 4; ++c)
            atomicAdd(&ctx[(((size_t)b*HEADS + h)*DHEAD + ty*4+r)*DHEAD + tx*4+c], acc[r][c]);
}

// ---------------------------------------------------------------------------
// K5: attn[b,s,h,e] = sum_d q_norm[b,s,h,d] * (ctx[b,h,d,e]/colsum[b,h,d])
// ---------------------------------------------------------------------------
__global__ __launch_bounds__(256)
void attn_rows(const unsigned short* __restrict__ QN, const float* __restrict__ ctx,
               const float* __restrict__ colsum, unsigned short* __restrict__ attn)
{
    __shared__ float cs[64][65];
    __shared__ float qs[64][65];
    const int rb = blockIdx.x, h = blockIdx.y, b = blockIdx.z;
    const int tid = threadIdx.x;
    const int tx = tid & 15, ty = tid >> 4;
    for (int t = tid; t < 4096; t += 256) {
        int d = t >> 6, e = t & 63;
        cs[d][e] = ctx[(((size_t)b*HEADS + h)*DHEAD + d)*DHEAD + e]
                 / colsum[b*E_DIM + h*DHEAD + d];
    }
    const int s0 = rb * 64;
    for (int t = tid; t < 4096; t += 256) {
        int i = t >> 6, d = t & 63;
        qs[i][d] = bf2f(QN[((size_t)b*SEQ + s0 + i)*E_DIM + h*DHEAD + d]);
    }
    __syncthreads();
    float acc[4][4] = {};
    for (int kk = 0; kk < 64; ++kk) {
        float a[4], bb[4];
        #pragma unroll
        for (int r = 0; r < 4; ++r) a[r] = qs[ty*4+r][kk];
        #pragma unroll
        for (int c = 0; c < 4; ++c) bb[c] = cs[kk][tx*4+c];
        #pragma unroll
        for (int r = 0; r < 4; ++r)
            #pragma unroll
            for (int c = 0; c < 4; ++c)
                acc[r][c] = fmaf(a[r], bb[c], acc[r][c]);
    }
    #pragma unroll
    for (int r = 0; r < 4; ++r) {
        union { unsigned short h4[4]; uint2 u; } o;
        #pragma unroll
        for (int c = 0; c < 4; ++c) o.h4[c] = f2bf(acc[r][c]);
        *(uint2*)(attn + ((size_t)b*SEQ + s0 + ty*4 + r)*E_DIM + h*DHEAD + tx*4) = o.u;
    }
}

// ---------------------------------------------------------------------------
extern "C" void kernel_launch(void* const* d_in, const int* in_sizes, int n_in,
                              void* d_out, int out_size, void* d_ws, size_t ws_size,
                              hipStream_t stream)
{
    const float* query = (const float*)d_in[0];
    const float* key   = (const float*)d_in[1];
    const float* value = (const float*)d_in[2];
    const unsigned char* mask = (const unsigned char*)d_in[3];
    const float* Wq  = (const float*)d_in[4];
    const float* bq  = (const float*)d_in[5];
    const float* Wk  = (const float*)d_in[6];
    const float* bk  = (const float*)d_in[7];
    const float* Wv  = (const float*)d_in[8];
    const float* bv  = (const float*)d_in[9];
    const float* qla = (const float*)d_in[10];
    const float* qlb = (const float*)d_in[11];
    const float* kla = (const float*)d_in[12];
    const float* klb = (const float*)d_in[13];
    const float* vla = (const float*)d_in[14];
    const float* vlb = (const float*)d_in[15];
    const float* Wo  = (const float*)d_in[16];
    const float* bo  = (const float*)d_in[17];

    const size_t NEEDED = 118767624ULL;
    if (ws_size < NEEDED) {   // report budget via absmax channel
        ws_sentinel<<<1, 256, 0, stream>>>((float*)d_out, (float)(ws_size >> 20));
        return;
    }

    char* ws = (char*)d_ws;
    float*          Weff   = (float*)(ws + 0);                     // 16 MB (4x 1024x1024 f32)
    unsigned short* qn     = (unsigned short*)(ws + 16777216);     // 32 MB
    unsigned short* kbuf   = (unsigned short*)(ws + 50331648);     // 32 MB (reused as attn)
    unsigned short* vbuf   = (unsigned short*)(ws + 83886080);     // 32 MB
    float*          part   = (float*)(ws + 117440512);             // 256 KB
    float*          colsum = (float*)(ws + 117702656);             // 16 KB
    float*          ctx    = (float*)(ws + 117719040);             // 1 MB
    unsigned short* attn   = kbuf;   // kbuf dead after context_partial

    prep_weights<<<16384, 256, 0, stream>>>(Wq, Wk, Wv, Wo, qla, qlb, kla, klb, vla, vlb, Weff);
    gemm128<0,0><<<dim3(8, 128), 256, 0, stream>>>(query, Weff,             bq, qn);
    q_softmax_inplace<<<65536, 256, 0, stream>>>(qn);
    gemm128<0,0><<<dim3(8, 128), 256, 0, stream>>>(key,   Weff + 1048576,   bk, kbuf);
    gemm128<0,0><<<dim3(8, 128), 256, 0, stream>>>(value, Weff + 2097152,   bv, vbuf);
    k_colsum_part<<<dim3(4, 16, BATCH), 256, 0, stream>>>(kbuf, mask, part);
    k_colsum_final<<<16, 256, 0, stream>>>(part, colsum);
    zero_ctx<<<1024, 256, 0, stream>>>(ctx);
    context_partial<<<dim3(HEADS, 16, BATCH), 256, 0, stream>>>(kbuf, vbuf, mask, ctx);
    attn_rows<<<dim3(64, HEADS, BATCH), 256, 0, stream>>>(qn, ctx, colsum, attn);
    gemm128<1,1><<<dim3(8, 128), 256, 0, stream>>>(attn, Weff + 3145728, bo, (float*)d_out);
}

// Round 5
// 568.810 us; speedup vs baseline: 3.2023x; 3.2023x over previous
//
#include <hip/hip_runtime.h>
#include <hip/hip_bf16.h>

#define E_DIM 1024
#define HEADS 16
#define DHEAD 64
#define RANK 8
#define BATCH 4
#define SEQ 4096
#define MTOT (BATCH*SEQ)

typedef short bf16x8 __attribute__((ext_vector_type(8)));
typedef float f32x4  __attribute__((ext_vector_type(4)));

__device__ __forceinline__ float bf2f(unsigned short u) {
    return __uint_as_float(((unsigned int)u) << 16);
}
__device__ __forceinline__ unsigned short f2bf(float f) {
    unsigned int x = __float_as_uint(f);
    unsigned int r = (x + 0x7fffu + ((x >> 16) & 1u)) >> 16;
    return (unsigned short)r;
}
// pack two f32 -> two bf16 (round-half-up; bias 2^-17, negligible)
__device__ __forceinline__ unsigned int pack2bf(float lo, float hi) {
    unsigned int l = __float_as_uint(lo), h = __float_as_uint(hi);
    return ((h + 0x8000u) & 0xFFFF0000u) | ((l + 0x8000u) >> 16);
}

// ---------------------------------------------------------------------------
// sentinel: report ws_size (MB) through the absmax channel if budget too small
// ---------------------------------------------------------------------------
__global__ __launch_bounds__(256)
void ws_sentinel(float* __restrict__ out, float mb)
{
    out[threadIdx.x] = mb;
}

// ---------------------------------------------------------------------------
// K1: Wt[g][n][k] = bf16( W[g][k][n] + sum_r A[g][k][r] B[g][r][n] )
// LoRA fused, output transposed [N,K] for contiguous-k MFMA fragments.
// 32x32 LDS tile transpose. g=3 (Wo): no LoRA.
// ---------------------------------------------------------------------------
__global__ __launch_bounds__(256)
void prep_weights_t(const float* __restrict__ Wq, const float* __restrict__ Wk,
                    const float* __restrict__ Wv, const float* __restrict__ Wo,
                    const float* __restrict__ qa, const float* __restrict__ qb,
                    const float* __restrict__ ka, const float* __restrict__ kb,
                    const float* __restrict__ va, const float* __restrict__ vb,
                    unsigned short* __restrict__ Wt)
{
    __shared__ float tile[32][33];
    const int n0 = blockIdx.x * 32;
    const int k0 = blockIdx.y * 32;
    const int g  = blockIdx.z;
    const float* W = (g==0)?Wq:(g==1)?Wk:(g==2)?Wv:Wo;
    const float* A = (g==0)?qa:(g==1)?ka:va;
    const float* Bm= (g==0)?qb:(g==1)?kb:vb;
    const int t  = threadIdx.x;
    const int r  = t >> 3;          // 0..31 (k-row on load, n-row on store)
    const int c4 = (t & 7) * 4;     // 4-wide chunk

    float4 v = *(const float4*)(W + (size_t)(k0 + r)*E_DIM + n0 + c4);
    float o0=v.x, o1=v.y, o2=v.z, o3=v.w;
    if (g < 3) {
        #pragma unroll
        for (int rr = 0; rr < RANK; ++rr) {
            float av = A[(k0 + r)*RANK + rr];
            const float* bp = Bm + (size_t)rr*E_DIM + n0 + c4;
            o0 = fmaf(av, bp[0], o0);
            o1 = fmaf(av, bp[1], o1);
            o2 = fmaf(av, bp[2], o2);
            o3 = fmaf(av, bp[3], o3);
        }
    }
    tile[r][c4+0]=o0; tile[r][c4+1]=o1; tile[r][c4+2]=o2; tile[r][c4+3]=o3;
    __syncthreads();
    union { unsigned short h[4]; uint2 u; } o;
    #pragma unroll
    for (int i = 0; i < 4; ++i) o.h[i] = f2bf(tile[c4+i][r]);
    *(uint2*)(Wt + (size_t)g*1048576 + (size_t)(n0 + r)*E_DIM + k0 + c4) = o.u;
}

// ---------------------------------------------------------------------------
// K2: MFMA GEMM  C[M,1024] = X[M,1024] @ Wt[1024,1024]^T + bias
// 128x128 tile, BK=32, 256 thr = 4 waves (2x2 of 64x64), 4x4 frags/wave,
// v_mfma_f32_16x16x32_bf16. LDS padded +8 bf16/row (80B) -> conflict-free
// b128 fragment reads. A-staging converts f32->bf16 in-flight when XF32.
// ---------------------------------------------------------------------------
#define LDA 40

template<int XF32, int OUTF32>
__global__ __launch_bounds__(256)
void mfma_gemm(const void* __restrict__ Xv, const unsigned short* __restrict__ Wt,
               const float* __restrict__ bias, void* __restrict__ outv)
{
    __shared__ __align__(16) unsigned short As[128*LDA];
    __shared__ __align__(16) unsigned short Bs[128*LDA];
    const int tid  = threadIdx.x;
    const int lane = tid & 63;
    const int w    = tid >> 6;
    const int wr   = w >> 1, wc = w & 1;
    const int i0   = blockIdx.y * 128;
    const int j0   = blockIdx.x * 128;
    const int l15  = lane & 15, lg = lane >> 4;

    const int srow = tid >> 2;            // staging row 0..63 (+64 on it=1)
    const int skc  = (tid & 3) * 8;       // staging k-chunk

    f32x4 acc[4][4];
    #pragma unroll
    for (int m = 0; m < 4; ++m)
        #pragma unroll
        for (int n = 0; n < 4; ++n) {
            f32x4 z = {0.f, 0.f, 0.f, 0.f};
            acc[m][n] = z;
        }

    for (int k0 = 0; k0 < E_DIM; k0 += 32) {
        // ---- stage A: 128 rows x 32 k ----
        if (XF32) {
            const float* X = (const float*)Xv;
            #pragma unroll
            for (int it = 0; it < 2; ++it) {
                const int row = it*64 + srow;
                const float* xp = X + (size_t)(i0+row)*E_DIM + k0 + skc;
                float4 u0 = *(const float4*)xp;
                float4 u1 = *(const float4*)(xp + 4);
                uint4 p;
                p.x = pack2bf(u0.x, u0.y);
                p.y = pack2bf(u0.z, u0.w);
                p.z = pack2bf(u1.x, u1.y);
                p.w = pack2bf(u1.z, u1.w);
                *(uint4*)&As[row*LDA + skc] = p;
            }
        } else {
            const unsigned short* X = (const unsigned short*)Xv;
            #pragma unroll
            for (int it = 0; it < 2; ++it) {
                const int row = it*64 + srow;
                uint4 u = *(const uint4*)(X + (size_t)(i0+row)*E_DIM + k0 + skc);
                *(uint4*)&As[row*LDA + skc] = u;
            }
        }
        // ---- stage B: 128 n-rows x 32 k from Wt[N,K] ----
        #pragma unroll
        for (int it = 0; it < 2; ++it) {
            const int row = it*64 + srow;
            uint4 u = *(const uint4*)(Wt + (size_t)(j0+row)*E_DIM + k0 + skc);
            *(uint4*)&Bs[row*LDA + skc] = u;
        }
        __syncthreads();
        // ---- compute: 8 ds_read_b128 + 16 MFMA per wave ----
        bf16x8 a[4], b[4];
        #pragma unroll
        for (int m = 0; m < 4; ++m)
            a[m] = *(const bf16x8*)&As[(wr*64 + m*16 + l15)*LDA + lg*8];
        #pragma unroll
        for (int n = 0; n < 4; ++n)
            b[n] = *(const bf16x8*)&Bs[(wc*64 + n*16 + l15)*LDA + lg*8];
        #pragma unroll
        for (int m = 0; m < 4; ++m)
            #pragma unroll
            for (int n = 0; n < 4; ++n)
                acc[m][n] = __builtin_amdgcn_mfma_f32_16x16x32_bf16(a[m], b[n], acc[m][n], 0, 0, 0);
        __syncthreads();
    }
    // ---- epilogue: C/D layout col=lane&15, row=(lane>>4)*4+reg ----
    #pragma unroll
    for (int n = 0; n < 4; ++n) {
        const int col = j0 + wc*64 + n*16 + l15;
        const float bv = bias[col];
        #pragma unroll
        for (int m = 0; m < 4; ++m) {
            const int rbase = i0 + wr*64 + m*16 + lg*4;
            #pragma unroll
            for (int r = 0; r < 4; ++r) {
                float val = acc[m][n][r] + bv;
                if (OUTF32)
                    ((float*)outv)[(size_t)(rbase + r)*E_DIM + col] = val;
                else
                    ((unsigned short*)outv)[(size_t)(rbase + r)*E_DIM + col] = f2bf(val);
            }
        }
    }
}

// ---------------------------------------------------------------------------
// K2b: in-place softmax over each head's 64 dims. One wave per (row, head).
// ---------------------------------------------------------------------------
__global__ __launch_bounds__(256)
void q_softmax_inplace(unsigned short* __restrict__ qn)
{
    const int gw   = (blockIdx.x * 256 + threadIdx.x) >> 6;  // 0..262143
    const int lane = threadIdx.x & 63;
    const int row  = gw >> 4;
    const int h    = gw & 15;
    const size_t base = (size_t)row * E_DIM + h * DHEAD;
    float x = bf2f(qn[base + lane]);
    float m = x;
    #pragma unroll
    for (int d = 32; d >= 1; d >>= 1) m = fmaxf(m, __shfl_xor(m, d));
    float e = __expf(x - m);
    float s = e;
    #pragma unroll
    for (int d = 32; d >= 1; d >>= 1) s += __shfl_xor(s, d);
    qn[base + lane] = f2bf(e / s);
}

// ---------------------------------------------------------------------------
// K3a/K3b: column sums of exp(k) over S (the k-softmax denominator)
// ---------------------------------------------------------------------------
__global__ __launch_bounds__(256)
void k_colsum_part(const unsigned short* __restrict__ K, const unsigned char* __restrict__ mask,
                   float* __restrict__ part)
{
    const int e  = blockIdx.x * 256 + threadIdx.x;   // 0..1023
    const int sb = blockIdx.y;                        // 0..15
    const int b  = blockIdx.z;
    const int s0 = sb * 256;
    const unsigned short* kp = K + ((size_t)b*SEQ + s0)*E_DIM + e;
    const unsigned char* mp = mask + b*SEQ + s0;
    float acc = 0.f;
    for (int s = 0; s < 256; ++s) {
        float kv = bf2f(kp[(size_t)s*E_DIM]);
        acc += mp[s] ? 0.f : __expf(kv);
    }
    part[((size_t)b*16 + sb)*E_DIM + e] = acc;
}

__global__ __launch_bounds__(256)
void k_colsum_final(const float* __restrict__ part, float* __restrict__ colsum)
{
    int idx = blockIdx.x * 256 + threadIdx.x;  // 4096
    int b = idx >> 10, e = idx & 1023;
    float s = 0.f;
    for (int p = 0; p < 16; ++p) s += part[((size_t)b*16 + p)*E_DIM + e];
    colsum[idx] = s;
}

__global__ __launch_bounds__(256)
void zero_ctx(float* __restrict__ ctx)
{
    ctx[blockIdx.x * 256 + threadIdx.x] = 0.f;
}

// ---------------------------------------------------------------------------
// K4: ctx[b,h,d,e] += sum_{s in chunk} exp(k[b,s,h,d]) * v[b,s,h,e]
// ---------------------------------------------------------------------------
__global__ __launch_bounds__(256)
void context_partial(const unsigned short* __restrict__ K, const unsigned short* __restrict__ V,
                     const unsigned char* __restrict__ mask, float* __restrict__ ctx)
{
    __shared__ float kx[32][65];
    __shared__ float vx[32][65];
    const int h = blockIdx.x, sb = blockIdx.y, b = blockIdx.z;
    const int tid = threadIdx.x;
    const int tx = tid & 15, ty = tid >> 4;
    float acc[4][4] = {};
    const int sbase = sb * 256;
    for (int sc = 0; sc < 256; sc += 32) {
        const int row = tid >> 3;
        const int cb  = (tid & 7) * 8;
        const int s   = sbase + sc + row;
        const size_t gof = ((size_t)b*SEQ + s)*E_DIM + h*DHEAD + cb;
        const bool msk = mask[b*SEQ + s] != 0;
        uint4 ku = *(const uint4*)(K + gof);
        uint4 vu = *(const uint4*)(V + gof);
        const unsigned short* ks = (const unsigned short*)&ku;
        const unsigned short* vs = (const unsigned short*)&vu;
        #pragma unroll
        for (int c = 0; c < 8; ++c) {
            kx[row][cb+c] = msk ? 0.f : __expf(bf2f(ks[c]));
            vx[row][cb+c] = bf2f(vs[c]);
        }
        __syncthreads();
        #pragma unroll
        for (int kk = 0; kk < 32; ++kk) {
            float a[4], bb[4];
            #pragma unroll
            for (int r = 0; r < 4; ++r) a[r] = kx[kk][ty*4+r];
            #pragma unroll
            for (int c = 0; c < 4; ++c) bb[c] = vx[kk][tx*4+c];
            #pragma unroll
            for (int r = 0; r < 4; ++r)
                #pragma unroll
                for (int c = 0; c < 4; ++c)
                    acc[r][c] = fmaf(a[r], bb[c], acc[r][c]);
        }
        __syncthreads();
    }
    #pragma unroll
    for (int r = 0; r < 4; ++r)
        #pragma unroll
        for (int c = 0; c < 4; ++c)
            atomicAdd(&ctx[(((size_t)b*HEADS + h)*DHEAD + ty*4+r)*DHEAD + tx*4+c], acc[r][c]);
}

// ---------------------------------------------------------------------------
// K5: attn[b,s,h,e] = sum_d q_norm[b,s,h,d] * (ctx[b,h,d,e]/colsum[b,h,d])
// ---------------------------------------------------------------------------
__global__ __launch_bounds__(256)
void attn_rows(const unsigned short* __restrict__ QN, const float* __restrict__ ctx,
               const float* __restrict__ colsum, unsigned short* __restrict__ attn)
{
    __shared__ float cs[64][65];
    __shared__ float qs[64][65];
    const int rb = blockIdx.x, h = blockIdx.y, b = blockIdx.z;
    const int tid = threadIdx.x;
    const int tx = tid & 15, ty = tid >> 4;
    for (int t = tid; t < 4096; t += 256) {
        int d = t >> 6, e = t & 63;
        cs[d][e] = ctx[(((size_t)b*HEADS + h)*DHEAD + d)*DHEAD + e]
                 / colsum[b*E_DIM + h*DHEAD + d];
    }
    const int s0 = rb * 64;
    for (int t = tid; t < 4096; t += 256) {
        int i = t >> 6, d = t & 63;
        qs[i][d] = bf2f(QN[((size_t)b*SEQ + s0 + i)*E_DIM + h*DHEAD + d]);
    }
    __syncthreads();
    float acc[4][4] = {};
    for (int kk = 0; kk < 64; ++kk) {
        float a[4], bb[4];
        #pragma unroll
        for (int r = 0; r < 4; ++r) a[r] = qs[ty*4+r][kk];
        #pragma unroll
        for (int c = 0; c < 4; ++c) bb[c] = cs[kk][tx*4+c];
        #pragma unroll
        for (int r = 0; r < 4; ++r)
            #pragma unroll
            for (int c = 0; c < 4; ++c)
                acc[r][c] = fmaf(a[r], bb[c], acc[r][c]);
    }
    #pragma unroll
    for (int r = 0; r < 4; ++r) {
        union { unsigned short h4[4]; uint2 u; } o;
        #pragma unroll
        for (int c = 0; c < 4; ++c) o.h4[c] = f2bf(acc[r][c]);
        *(uint2*)(attn + ((size_t)b*SEQ + s0 + ty*4 + r)*E_DIM + h*DHEAD + tx*4) = o.u;
    }
}

// ---------------------------------------------------------------------------
extern "C" void kernel_launch(void* const* d_in, const int* in_sizes, int n_in,
                              void* d_out, int out_size, void* d_ws, size_t ws_size,
                              hipStream_t stream)
{
    const float* query = (const float*)d_in[0];
    const float* key   = (const float*)d_in[1];
    const float* value = (const float*)d_in[2];
    const unsigned char* mask = (const unsigned char*)d_in[3];
    const float* Wq  = (const float*)d_in[4];
    const float* bq  = (const float*)d_in[5];
    const float* Wk  = (const float*)d_in[6];
    const float* bk  = (const float*)d_in[7];
    const float* Wv  = (const float*)d_in[8];
    const float* bv  = (const float*)d_in[9];
    const float* qla = (const float*)d_in[10];
    const float* qlb = (const float*)d_in[11];
    const float* kla = (const float*)d_in[12];
    const float* klb = (const float*)d_in[13];
    const float* vla = (const float*)d_in[14];
    const float* vlb = (const float*)d_in[15];
    const float* Wo  = (const float*)d_in[16];
    const float* bo  = (const float*)d_in[17];

    const size_t NEEDED = 110379008ULL;
    if (ws_size < NEEDED) {   // report budget (MB) via absmax channel
        ws_sentinel<<<1, 256, 0, stream>>>((float*)d_out, (float)(ws_size >> 20));
        return;
    }

    char* ws = (char*)d_ws;
    unsigned short* Wt     = (unsigned short*)(ws + 0);            // 8 MB (4x [1024n][1024k] bf16)
    unsigned short* qn     = (unsigned short*)(ws + 8388608);      // 32 MB
    unsigned short* kbuf   = (unsigned short*)(ws + 41943040);     // 32 MB (reused as attn)
    unsigned short* vbuf   = (unsigned short*)(ws + 75497472);     // 32 MB
    float*          part   = (float*)(ws + 109051904);             // 256 KB
    float*          colsum = (float*)(ws + 109314048);             // 16 KB
    float*          ctx    = (float*)(ws + 109330432);             // 1 MB
    unsigned short* attn   = kbuf;   // kbuf dead after context_partial

    prep_weights_t<<<dim3(32, 32, 4), 256, 0, stream>>>(Wq, Wk, Wv, Wo,
                                                        qla, qlb, kla, klb, vla, vlb, Wt);
    mfma_gemm<1,0><<<dim3(8, 128), 256, 0, stream>>>(query, Wt,           bq, qn);
    q_softmax_inplace<<<65536, 256, 0, stream>>>(qn);
    mfma_gemm<1,0><<<dim3(8, 128), 256, 0, stream>>>(key,   Wt + 1048576, bk, kbuf);
    mfma_gemm<1,0><<<dim3(8, 128), 256, 0, stream>>>(value, Wt + 2097152, bv, vbuf);
    k_colsum_part<<<dim3(4, 16, BATCH), 256, 0, stream>>>(kbuf, mask, part);
    k_colsum_final<<<16, 256, 0, stream>>>(part, colsum);
    zero_ctx<<<1024, 256, 0, stream>>>(ctx);
    context_partial<<<dim3(HEADS, 16, BATCH), 256, 0, stream>>>(kbuf, vbuf, mask, ctx);
    attn_rows<<<dim3(64, HEADS, BATCH), 256, 0, stream>>>(qn, ctx, colsum, attn);
    mfma_gemm<0,1><<<dim3(8, 128), 256, 0, stream>>>(attn, Wt + 3145728, bo, (float*)d_out);
}